// Round 1
// baseline (5022.449 us; speedup 1.0000x reference)
//
#include <hip/hip_runtime.h>
#include <math.h>

#define B_ 32
#define S_ 256
#define H_ 2048
#define NH_ 16
#define HD_ 128
#define M_ (B_*S_)

// ---------------------------------------------------------------------------
// GEMM: C = X @ W^T.  X:[M,K] row-major, W:[N,K] row-major (both dotted along K).
// mode 0: scatter C into [B, NH, S, HD] (head-major) for attention.
// mode 1: plain row-major [M, N] (final output projection).
// 128x128 tile, BK=16, 256 threads, 8x8 micro-tile. VALU-bound fp32 baseline.
// ---------------------------------------------------------------------------
#define BM 128
#define BN 128
#define BK 16

__global__ __launch_bounds__(256, 2) void gemm_xwt(
    const float* __restrict__ X, const float* __restrict__ W,
    float* __restrict__ out, int mode)
{
    __shared__ __align__(16) float As[BK][BM];
    __shared__ __align__(16) float Bs[BK][BN];

    const int tid = threadIdx.x;
    const int bx = blockIdx.x;          // N tile (== head index in mode 0)
    const int by = blockIdx.y;          // M tile
    const int ty = tid >> 4;            // 0..15 -> rows ty*8..+7
    const int tx = tid & 15;            // 0..15 -> cols {tx*4..+3, 64+tx*4..+3}

    const float* Xa = X + (size_t)by * BM * H_;
    const float* Wa = W + (size_t)bx * BN * H_;

    float acc[8][8];
#pragma unroll
    for (int i = 0; i < 8; ++i)
#pragma unroll
        for (int j = 0; j < 8; ++j) acc[i][j] = 0.f;

    const int lr = tid >> 2;            // 0..63
    const int lc = (tid & 3) << 2;      // 0,4,8,12

    for (int kt = 0; kt < H_; kt += BK) {
        // global loads first (prefetch ahead of the barrier)
        float4 a0 = *(const float4*)(Xa + (size_t)lr * H_ + kt + lc);
        float4 a1 = *(const float4*)(Xa + (size_t)(lr + 64) * H_ + kt + lc);
        float4 b0 = *(const float4*)(Wa + (size_t)lr * H_ + kt + lc);
        float4 b1 = *(const float4*)(Wa + (size_t)(lr + 64) * H_ + kt + lc);
        __syncthreads();                 // previous compute done
        As[lc+0][lr] = a0.x; As[lc+1][lr] = a0.y; As[lc+2][lr] = a0.z; As[lc+3][lr] = a0.w;
        As[lc+0][lr+64] = a1.x; As[lc+1][lr+64] = a1.y; As[lc+2][lr+64] = a1.z; As[lc+3][lr+64] = a1.w;
        Bs[lc+0][lr] = b0.x; Bs[lc+1][lr] = b0.y; Bs[lc+2][lr] = b0.z; Bs[lc+3][lr] = b0.w;
        Bs[lc+0][lr+64] = b1.x; Bs[lc+1][lr+64] = b1.y; Bs[lc+2][lr+64] = b1.z; Bs[lc+3][lr+64] = b1.w;
        __syncthreads();
#pragma unroll
        for (int kk = 0; kk < BK; ++kk) {
            float4 av0 = *(const float4*)&As[kk][ty*8];
            float4 av1 = *(const float4*)&As[kk][ty*8+4];
            float4 bv0 = *(const float4*)&Bs[kk][tx*4];
            float4 bv1 = *(const float4*)&Bs[kk][64 + tx*4];
            float a[8] = {av0.x, av0.y, av0.z, av0.w, av1.x, av1.y, av1.z, av1.w};
            float b[8] = {bv0.x, bv0.y, bv0.z, bv0.w, bv1.x, bv1.y, bv1.z, bv1.w};
#pragma unroll
            for (int i = 0; i < 8; ++i) {
#pragma unroll
                for (int j = 0; j < 8; ++j)
                    acc[i][j] = fmaf(a[i], b[j], acc[i][j]);
            }
        }
    }

    if (mode == 0) {
        const int h = bx;               // BN == HD: one head per block column
#pragma unroll
        for (int i = 0; i < 8; ++i) {
            int m = by * BM + ty * 8 + i;
            int bb = m >> 8, ss = m & (S_ - 1);
            float* o = out + ((size_t)(bb * NH_ + h) * S_ + ss) * HD_;
            *(float4*)(o + tx*4)      = make_float4(acc[i][0], acc[i][1], acc[i][2], acc[i][3]);
            *(float4*)(o + 64 + tx*4) = make_float4(acc[i][4], acc[i][5], acc[i][6], acc[i][7]);
        }
    } else {
#pragma unroll
        for (int i = 0; i < 8; ++i) {
            int m = by * BM + ty * 8 + i;
            float* o = out + (size_t)m * H_ + bx * BN;
            *(float4*)(o + tx*4)      = make_float4(acc[i][0], acc[i][1], acc[i][2], acc[i][3]);
            *(float4*)(o + 64 + tx*4) = make_float4(acc[i][4], acc[i][5], acc[i][6], acc[i][7]);
        }
    }
}

// ---------------------------------------------------------------------------
// RoPE in-place on q and k, layout [B, NH, S, HD]. Thread handles pair (i, i+64).
// ---------------------------------------------------------------------------
__global__ __launch_bounds__(256) void rope_kernel(float* __restrict__ q, float* __restrict__ k)
{
    const int idx = blockIdx.x * 256 + threadIdx.x;   // 0 .. B*NH*S*64-1
    float* p = blockIdx.y ? k : q;
    const int i  = idx & 63;
    const int s  = (idx >> 6) & (S_ - 1);
    const int bh = idx >> 14;
    const size_t base = ((size_t)bh * S_ + s) * HD_;
    const float f = expf((float)i * -0.14391156831212788f);  // 10000^(-i/64)
    const float ang = (float)s * f;
    const float c = cosf(ang), sn = sinf(ang);
    const float x0 = p[base + i], x1 = p[base + i + 64];
    p[base + i]      = x0 * c - x1 * sn;
    p[base + i + 64] = x1 * c + x0 * sn;
}

// ---------------------------------------------------------------------------
// Attention: block = 256 threads handles one (b,h) and 32 q rows.
// LDS: Qs 16K + KVs 16K (xor-swizzled, conflict-free float4 reads) + Sc 32K = 64K.
// Softmax reductions via __shfl_xor over 8-lane groups (threads of one row are
// adjacent lanes). Scores normalized in-place so PV reads final probabilities.
// ---------------------------------------------------------------------------
#define SCALE 0.08838834764831845f   // 1/sqrt(128)

__device__ __forceinline__ int sc_idx(int r, int j) { return (r << 8) + (j ^ (r << 2)); }

__global__ __launch_bounds__(256, 2) void attn_kernel(
    const float* __restrict__ Q, const float* __restrict__ K,
    const float* __restrict__ V, float* __restrict__ out)
{
    __shared__ __align__(16) float Qs[32][128];
    __shared__ __align__(16) float KVs[32][128];
    __shared__ float Sc[32 * 256];

    const int tid = threadIdx.x;
    const int bh  = blockIdx.x;          // b*NH + h
    const int qt0 = blockIdx.y << 5;     // q-row tile base

    const float* Qg = Q + ((size_t)bh * S_ + qt0) * HD_;
    const float* Kg = K + (size_t)bh * S_ * HD_;
    const float* Vg = V + (size_t)bh * S_ * HD_;

    // stage Q tile (32x128), column-swizzled by c ^ (r&28)
#pragma unroll
    for (int p = 0; p < 4; ++p) {
        int f4 = tid + (p << 8);
        int r = f4 >> 5, c = (f4 & 31) << 2;
        float4 val = ((const float4*)Qg)[f4];
        *(float4*)&Qs[r][c ^ (r & 28)] = val;
    }

    const int qh = tid >> 4;   // 0..15 -> q rows {qh*2, qh*2+1}
    const int jh = tid & 15;   // 0..15 -> j cols {jh*2, jh*2+1}

    // ---- scores: S = scale * Q K^T ----
    for (int kt = 0; kt < 8; ++kt) {
        __syncthreads();
#pragma unroll
        for (int p = 0; p < 4; ++p) {
            int f4 = tid + (p << 8);
            int r = f4 >> 5, c = (f4 & 31) << 2;
            float4 val = ((const float4*)(Kg + ((size_t)kt << 5) * HD_))[f4];
            *(float4*)&KVs[r][c ^ (r & 28)] = val;
        }
        __syncthreads();
        float s00 = 0.f, s01 = 0.f, s10 = 0.f, s11 = 0.f;
        const int q0 = qh * 2, q1 = q0 + 1, j0 = jh * 2, j1 = j0 + 1;
        for (int dc = 0; dc < 128; dc += 4) {
            float4 qa = *(const float4*)&Qs[q0][dc ^ (q0 & 28)];
            float4 qb = *(const float4*)&Qs[q1][dc ^ (q1 & 28)];
            float4 ka = *(const float4*)&KVs[j0][dc ^ (j0 & 28)];
            float4 kb = *(const float4*)&KVs[j1][dc ^ (j1 & 28)];
            s00 += qa.x*ka.x + qa.y*ka.y + qa.z*ka.z + qa.w*ka.w;
            s01 += qa.x*kb.x + qa.y*kb.y + qa.z*kb.z + qa.w*kb.w;
            s10 += qb.x*ka.x + qb.y*ka.y + qb.z*ka.z + qb.w*ka.w;
            s11 += qb.x*kb.x + qb.y*kb.y + qb.z*kb.z + qb.w*kb.w;
        }
        const int jj0 = (kt << 5) + j0;
        Sc[sc_idx(q0, jj0)]     = s00 * SCALE;
        Sc[sc_idx(q0, jj0 + 1)] = s01 * SCALE;
        Sc[sc_idx(q1, jj0)]     = s10 * SCALE;
        Sc[sc_idx(q1, jj0 + 1)] = s11 * SCALE;
    }
    __syncthreads();

    // ---- softmax (8 adjacent lanes per row; shuffle reductions) ----
    {
        const int row = tid >> 3, seg = tid & 7;
        float mx = -1e30f;
        for (int c = 0; c < 32; ++c)
            mx = fmaxf(mx, Sc[sc_idx(row, (seg << 5) + c)]);
#pragma unroll
        for (int o = 1; o < 8; o <<= 1) mx = fmaxf(mx, __shfl_xor(mx, o));
        float sum = 0.f;
        for (int c = 0; c < 32; ++c) {
            int ix = sc_idx(row, (seg << 5) + c);
            float e = __expf(Sc[ix] - mx);
            Sc[ix] = e;
            sum += e;
        }
#pragma unroll
        for (int o = 1; o < 8; o <<= 1) sum += __shfl_xor(sum, o);
        const float rinv = 1.f / sum;
        for (int c = 0; c < 32; ++c)
            Sc[sc_idx(row, (seg << 5) + c)] *= rinv;
    }

    // ---- O = P V ----
    const int dg  = tid & 15;   // d = dg*8 .. +7
    const int qh2 = tid >> 4;   // rows {qh2*2, qh2*2+1}
    float4 a0 = make_float4(0,0,0,0), a1 = make_float4(0,0,0,0);
    float4 b0 = make_float4(0,0,0,0), b1 = make_float4(0,0,0,0);
    const int r0 = qh2 * 2, r1 = r0 + 1;
    for (int kt = 0; kt < 8; ++kt) {
        __syncthreads();
#pragma unroll
        for (int p = 0; p < 4; ++p) {
            int f4 = tid + (p << 8);
            int r = f4 >> 5, c = (f4 & 31) << 2;
            float4 val = ((const float4*)(Vg + ((size_t)kt << 5) * HD_))[f4];
            *(float4*)&KVs[r][c ^ (r & 28)] = val;
        }
        __syncthreads();
        for (int j = 0; j < 32; ++j) {
            const float p0 = Sc[sc_idx(r0, (kt << 5) + j)];
            const float p1 = Sc[sc_idx(r1, (kt << 5) + j)];
            const int cb = dg << 3;
            float4 v0 = *(const float4*)&KVs[j][cb ^ (j & 28)];
            float4 v1 = *(const float4*)&KVs[j][(cb + 4) ^ (j & 28)];
            a0.x = fmaf(p0, v0.x, a0.x); a0.y = fmaf(p0, v0.y, a0.y);
            a0.z = fmaf(p0, v0.z, a0.z); a0.w = fmaf(p0, v0.w, a0.w);
            a1.x = fmaf(p0, v1.x, a1.x); a1.y = fmaf(p0, v1.y, a1.y);
            a1.z = fmaf(p0, v1.z, a1.z); a1.w = fmaf(p0, v1.w, a1.w);
            b0.x = fmaf(p1, v0.x, b0.x); b0.y = fmaf(p1, v0.y, b0.y);
            b0.z = fmaf(p1, v0.z, b0.z); b0.w = fmaf(p1, v0.w, b0.w);
            b1.x = fmaf(p1, v1.x, b1.x); b1.y = fmaf(p1, v1.y, b1.y);
            b1.z = fmaf(p1, v1.z, b1.z); b1.w = fmaf(p1, v1.w, b1.w);
        }
    }

    // write [B, S, H] so final projection is a plain row-major GEMM
    const int bb = bh >> 4, h = bh & 15;
    {
        const int s0 = qt0 + r0;
        float* o = out + ((size_t)(bb * S_ + s0)) * H_ + (h << 7) + (dg << 3);
        *(float4*)o       = a0;
        *(float4*)(o + 4) = a1;
        o += H_;
        *(float4*)o       = b0;
        *(float4*)(o + 4) = b1;
    }
}

// ---------------------------------------------------------------------------
extern "C" void kernel_launch(void* const* d_in, const int* in_sizes, int n_in,
                              void* d_out, int out_size, void* d_ws, size_t ws_size,
                              hipStream_t stream)
{
    const float* X  = (const float*)d_in[0];
    const float* Wq = (const float*)d_in[1];
    const float* Wk = (const float*)d_in[2];
    const float* Wv = (const float*)d_in[3];
    const float* Wo = (const float*)d_in[4];
    float* outp = (float*)d_out;

    float* q   = (float*)d_ws;                      // [B,NH,S,HD] 67MB
    float* kbf = q   + (size_t)M_ * H_;
    float* vbf = kbf + (size_t)M_ * H_;
    float* att = vbf + (size_t)M_ * H_;             // [B,S,H]

    dim3 gg(H_ / BN, M_ / BM);                      // (16, 64)
    gemm_xwt<<<gg, 256, 0, stream>>>(X, Wq, q,   0);
    gemm_xwt<<<gg, 256, 0, stream>>>(X, Wk, kbf, 0);
    gemm_xwt<<<gg, 256, 0, stream>>>(X, Wv, vbf, 0);
    rope_kernel<<<dim3((B_*NH_*S_*64)/256, 2), 256, 0, stream>>>(q, kbf);
    attn_kernel<<<dim3(B_*NH_, S_/32), 256, 0, stream>>>(q, kbf, vbf, att);
    gemm_xwt<<<gg, 256, 0, stream>>>(att, Wo, outp, 1);
}

// Round 2
// 1310.889 us; speedup vs baseline: 3.8313x; 3.8313x over previous
//
#include <hip/hip_runtime.h>
#include <math.h>

#define B_ 32
#define S_ 256
#define H_ 2048
#define NH_ 16
#define HD_ 128
#define M_ (B_*S_)
#define K_ H_

typedef unsigned short u16;
typedef unsigned int   u32;
typedef __attribute__((ext_vector_type(8))) short  short8;   // 8 bf16 (4 VGPRs) MFMA A/B frag
typedef __attribute__((ext_vector_type(8))) unsigned short ushort8;
typedef __attribute__((ext_vector_type(4))) float  floatx4;  // MFMA C/D frag

typedef __attribute__((address_space(3))) u32 lds_u32;
typedef __attribute__((address_space(1))) const u32 glb_u32;

__device__ __forceinline__ u16 rne_bf16(float f) {
    u32 u = __float_as_uint(f);
    return (u16)((u + 0x7fffu + ((u >> 16) & 1u)) >> 16);
}
__device__ __forceinline__ float bf16_to_f(u16 h) {
    return __uint_as_float(((u32)h) << 16);
}
// async 16B global->LDS; lds addr must be wave-uniform base (+ lane*16 implicit)
__device__ __forceinline__ void gll16(const u16* g, u16* l) {
    __builtin_amdgcn_global_load_lds((glb_u32*)g, (lds_u32*)l, 16, 0, 0);
}

// ---------------------------------------------------------------------------
// fp32 -> (hi, lo) bf16 split.  x = hi + lo + O(2^-17 |x|)
// ---------------------------------------------------------------------------
__global__ __launch_bounds__(256) void split_kernel(const float* __restrict__ x,
    u16* __restrict__ hi, u16* __restrict__ lo, int n4)
{
    int i = blockIdx.x * 256 + threadIdx.x;
    if (i >= n4) return;
    float4 v = ((const float4*)x)[i];
    float vv[4] = {v.x, v.y, v.z, v.w};
    u16 h[4], l[4];
#pragma unroll
    for (int j = 0; j < 4; ++j) {
        h[j] = rne_bf16(vv[j]);
        l[j] = rne_bf16(vv[j] - bf16_to_f(h[j]));
    }
    ((ushort4*)hi)[i] = make_ushort4(h[0], h[1], h[2], h[3]);
    ((ushort4*)lo)[i] = make_ushort4(l[0], l[1], l[2], l[3]);
}

// ---------------------------------------------------------------------------
// C = A @ B^T via 3-pass split-bf16 MFMA (hi*hi + hi*lo + lo*hi), fp32 acc.
// A: [M,2048] as hi/lo bf16. B: [2048,2048] as hi/lo bf16 (row n dotted on K).
// 128x128 tile, BK=32, 256 thr = 4 waves, wave tile 64x64 = 4x4 MFMA 16x16x32.
// LDS plane-major: chunk (row,kc) at slot kc*128+row -> conflict-free b128 frag reads.
// mode 0: write bf16 head-major [B,NH,S,HD] (bx == head).  mode 1: fp32 [M,2048].
// ---------------------------------------------------------------------------
__global__ __launch_bounds__(256, 2) void gemm_split(
    const u16* __restrict__ Ahi, const u16* __restrict__ Alo,
    const u16* __restrict__ Bhi, const u16* __restrict__ Blo,
    void* __restrict__ outv, int mode)
{
    __shared__ u16 sAhi[4096], sAlo[4096], sBhi[4096], sBlo[4096];  // 8KB each

    const int tid = threadIdx.x;
    const int lane = tid & 63, w = tid >> 6;
    const int bx = blockIdx.x, by = blockIdx.y;
    const int wm = w >> 1, wn = w & 1;
    const int r15 = lane & 15, quad = lane >> 4;

    const u16* srcs[4] = {Ahi, Alo, Bhi, Blo};
    u16* dsts[4] = {sAhi, sAlo, sBhi, sBlo};
    const int tile0[4] = {by*128, by*128, bx*128, bx*128};

    const u16* gp[2][4];
    u16*       lp[2][4];
#pragma unroll
    for (int rep = 0; rep < 2; ++rep) {
        int slot = (w*2 + rep)*64 + lane;       // 0..511
        int kc = slot >> 7, row = slot & 127;   // plane kc, row
#pragma unroll
        for (int b = 0; b < 4; ++b) {
            gp[rep][b] = srcs[b] + (size_t)(tile0[b] + row) * K_ + kc*8;
            lp[rep][b] = dsts[b] + (w*2 + rep)*512;   // wave-uniform 1KB segment
        }
    }

    const floatx4 fzero = {0.f, 0.f, 0.f, 0.f};
    floatx4 acc[4][4];
#pragma unroll
    for (int mi = 0; mi < 4; ++mi)
#pragma unroll
        for (int ni = 0; ni < 4; ++ni) acc[mi][ni] = fzero;

    for (int kt = 0; kt < K_/32; ++kt) {
#pragma unroll
        for (int rep = 0; rep < 2; ++rep)
#pragma unroll
            for (int b = 0; b < 4; ++b) {
                gll16(gp[rep][b], lp[rep][b]);
                gp[rep][b] += 32;               // next K-tile (64 B)
            }
        __syncthreads();                        // vmcnt(0) drain lands the loads

        short8 ah[4], al[4], bh[4], bl[4];
#pragma unroll
        for (int mi = 0; mi < 4; ++mi) {
            int idx = (quad*128 + wm*64 + mi*16 + r15) * 8;
            ah[mi] = *(const short8*)&sAhi[idx];
            al[mi] = *(const short8*)&sAlo[idx];
        }
#pragma unroll
        for (int ni = 0; ni < 4; ++ni) {
            int idx = (quad*128 + wn*64 + ni*16 + r15) * 8;
            bh[ni] = *(const short8*)&sBhi[idx];
            bl[ni] = *(const short8*)&sBlo[idx];
        }
#pragma unroll
        for (int mi = 0; mi < 4; ++mi)
#pragma unroll
            for (int ni = 0; ni < 4; ++ni) {
                acc[mi][ni] = __builtin_amdgcn_mfma_f32_16x16x32_bf16(ah[mi], bh[ni], acc[mi][ni], 0, 0, 0);
                acc[mi][ni] = __builtin_amdgcn_mfma_f32_16x16x32_bf16(ah[mi], bl[ni], acc[mi][ni], 0, 0, 0);
                acc[mi][ni] = __builtin_amdgcn_mfma_f32_16x16x32_bf16(al[mi], bh[ni], acc[mi][ni], 0, 0, 0);
            }
        __syncthreads();                        // compute done before restage
    }

    // C/D layout: col = lane&15, row = quad*4 + reg  [m89/m91 verified]
    if (mode == 0) {
        u16* out = (u16*)outv;                  // [B, NH, S, HD], head h == bx
#pragma unroll
        for (int mi = 0; mi < 4; ++mi)
#pragma unroll
            for (int r = 0; r < 4; ++r) {
                int m = by*128 + wm*64 + mi*16 + quad*4 + r;
                int bb = m >> 8, ss = m & 255;
                size_t base = (((size_t)(bb*NH_ + bx)) * S_ + ss) * HD_ + wn*64 + r15;
#pragma unroll
                for (int ni = 0; ni < 4; ++ni)
                    out[base + ni*16] = rne_bf16(acc[mi][ni][r]);
            }
    } else {
        float* out = (float*)outv;              // [M, 2048]
#pragma unroll
        for (int mi = 0; mi < 4; ++mi)
#pragma unroll
            for (int r = 0; r < 4; ++r) {
                int m = by*128 + wm*64 + mi*16 + quad*4 + r;
                size_t base = (size_t)m * H_ + bx*128 + wn*64 + r15;
#pragma unroll
                for (int ni = 0; ni < 4; ++ni)
                    out[base + ni*16] = acc[mi][ni][r];
            }
    }
}

// ---------------------------------------------------------------------------
// RoPE in-place on bf16 q,k in [B,NH,S,HD]; pair (i, i+64). Accurate cosf/sinf.
// ---------------------------------------------------------------------------
__global__ __launch_bounds__(256) void rope_bf(u16* __restrict__ q, u16* __restrict__ k)
{
    int idx = blockIdx.x * 256 + threadIdx.x;       // pair index
    u16* p = blockIdx.y ? k : q;
    int i  = idx & 63;
    int s  = (idx >> 6) & (S_ - 1);
    int bh = idx >> 14;
    size_t base = ((size_t)bh * S_ + s) * HD_;
    float f = expf((float)i * -0.14391156831212788f);   // 10000^(-i/64)
    float ang = (float)s * f;
    float c = cosf(ang), sn = sinf(ang);
    float x0 = bf16_to_f(p[base + i]), x1 = bf16_to_f(p[base + i + 64]);
    p[base + i]      = rne_bf16(x0 * c - x1 * sn);
    p[base + i + 64] = rne_bf16(x1 * c + x0 * sn);
}

// ---------------------------------------------------------------------------
// Attention, bf16 MFMA. Block = 256 thr (4 waves) handles (b,h) x 64 q-rows.
// Scores kept in C-layout registers (wave w owns q-rows w*16..+15, all 256 cols);
// softmax via 16-lane shuffle; P -> LDS (plane-major) -> A-operand for PV.
// LDS 48KB: shQK = Qs(16K)+Ks(16K) reused as Pb(32K); shV = Vt transposed (16K).
// Output written as hi/lo split bf16 [M, 2048] for the final split GEMM.
// ---------------------------------------------------------------------------
#define SCALE 0.08838834764831845f

__global__ __launch_bounds__(256) void attn_mfma(
    const u16* __restrict__ Q, const u16* __restrict__ K, const u16* __restrict__ V,
    u16* __restrict__ Ohi, u16* __restrict__ Olo)
{
    __shared__ u16 shQK[16384];
    __shared__ u16 shV[8192];
    u16* Qs = shQK;            // planes [16][64] chunks of 8 bf16
    u16* Ks = shQK + 8192;     // planes [16][64]
    u16* Pb = shQK;            // planes [32][64]  (after Qs/Ks dead)

    const int tid = threadIdx.x;
    const int lane = tid & 63, w = tid >> 6;
    const int r15 = lane & 15, quad = lane >> 4;
    const int bh = blockIdx.x;
    const int q0 = blockIdx.y << 6;
    const int wq = w * 16;

    const u16* Qg = Q + ((size_t)bh * S_ + q0) * HD_;
    const u16* Kg = K + (size_t)bh * S_ * HD_;
    const u16* Vg = V + (size_t)bh * S_ * HD_;

    // stage Q tile 64x128 -> plane-major
#pragma unroll
    for (int p = 0; p < 4; ++p) {
        int task = tid + (p << 8);
        int r = task & 63, c = task >> 6;
        *(uint4*)&Qs[(c*64 + r)*8] = *(const uint4*)&Qg[(size_t)r*HD_ + c*8];
    }

    const floatx4 fzero = {0.f, 0.f, 0.f, 0.f};
    floatx4 sc[4][4];                          // [kt][ni]; rows wq+quad*4+reg
    for (int kt = 0; kt < 4; ++kt) {
        __syncthreads();
#pragma unroll
        for (int p = 0; p < 4; ++p) {
            int task = tid + (p << 8);
            int r = task & 63, c = task >> 6;
            *(uint4*)&Ks[(c*64 + r)*8] = *(const uint4*)&Kg[(size_t)(kt*64 + r)*HD_ + c*8];
        }
        __syncthreads();
#pragma unroll
        for (int ni = 0; ni < 4; ++ni) sc[kt][ni] = fzero;
#pragma unroll
        for (int ks = 0; ks < 4; ++ks) {
            short8 a = *(const short8*)&Qs[((ks*4 + quad)*64 + wq + r15)*8];
#pragma unroll
            for (int ni = 0; ni < 4; ++ni) {
                short8 b = *(const short8*)&Ks[((ks*4 + quad)*64 + ni*16 + r15)*8];
                sc[kt][ni] = __builtin_amdgcn_mfma_f32_16x16x32_bf16(a, b, sc[kt][ni], 0, 0, 0);
            }
        }
    }
    __syncthreads();   // all Qs/Ks reads complete before Pb overwrites them

    // ---- softmax in registers (rows wq+quad*4+r; 16 col-lanes via shuffle) ----
#pragma unroll
    for (int kt = 0; kt < 4; ++kt)
#pragma unroll
        for (int ni = 0; ni < 4; ++ni) sc[kt][ni] *= SCALE;

    float rinv4[4], mrow4[4];
#pragma unroll
    for (int r = 0; r < 4; ++r) {
        float m = -1e30f;
#pragma unroll
        for (int kt = 0; kt < 4; ++kt)
#pragma unroll
            for (int ni = 0; ni < 4; ++ni) m = fmaxf(m, sc[kt][ni][r]);
#pragma unroll
        for (int o = 1; o < 16; o <<= 1) m = fmaxf(m, __shfl_xor(m, o));
        mrow4[r] = m;
    }
#pragma unroll
    for (int r = 0; r < 4; ++r) {
        float ssum = 0.f;
#pragma unroll
        for (int kt = 0; kt < 4; ++kt)
#pragma unroll
            for (int ni = 0; ni < 4; ++ni) {
                float e = __expf(sc[kt][ni][r] - mrow4[r]);
                sc[kt][ni][r] = e;
                ssum += e;
            }
#pragma unroll
        for (int o = 1; o < 16; o <<= 1) ssum += __shfl_xor(ssum, o);
        rinv4[r] = 1.f / ssum;
    }
    // write P bf16 -> Pb plane-major: elem(row,col) at chunk (col>>3)*64+row
#pragma unroll
    for (int r = 0; r < 4; ++r) {
        int row = wq + quad*4 + r;
#pragma unroll
        for (int kt = 0; kt < 4; ++kt)
#pragma unroll
            for (int ni = 0; ni < 4; ++ni) {
                int col = kt*64 + ni*16 + r15;
                Pb[((col >> 3)*64 + row)*8 + (col & 7)] = rne_bf16(sc[kt][ni][r] * rinv4[r]);
            }
    }

    // ---- O = P V ----
    floatx4 oacc[8];
#pragma unroll
    for (int di = 0; di < 8; ++di) oacc[di] = fzero;

    for (int vt = 0; vt < 4; ++vt) {
        __syncthreads();
        // stage V tile transposed: Vt planes [8][128] chunks; elem(d,s') at chunk (s'>>3)*128+d
#pragma unroll
        for (int p = 0; p < 4; ++p) {
            int task = tid + (p << 8);
            int r = task & 63, dc = task >> 6;          // s' = r, d-chunk dc
            ushort8 v = *(const ushort8*)&Vg[(size_t)(vt*64 + r)*HD_ + dc*8];
#pragma unroll
            for (int j = 0; j < 8; ++j)
                shV[(((r >> 3)*128) + dc*8 + j)*8 + (r & 7)] = v[j];
        }
        __syncthreads();
#pragma unroll
        for (int ks = 0; ks < 2; ++ks) {
            int colbase = vt*64 + ks*32 + quad*8;
            short8 a = *(const short8*)&Pb[((colbase >> 3)*64 + wq + r15)*8];
            int sp = ks*32 + quad*8;
#pragma unroll
            for (int di = 0; di < 8; ++di) {
                short8 b = *(const short8*)&shV[((sp >> 3)*128 + di*16 + r15)*8];
                oacc[di] = __builtin_amdgcn_mfma_f32_16x16x32_bf16(a, b, oacc[di], 0, 0, 0);
            }
        }
    }

    // epilogue: att[m][n] -> hi/lo split bf16, m = b*256+s, n = h*128 + d
    const int brow = bh >> 4, h = bh & 15;
#pragma unroll
    for (int r = 0; r < 4; ++r) {
        size_t base = ((size_t)(brow*S_ + q0 + wq + quad*4 + r)) * H_ + h*128 + r15;
#pragma unroll
        for (int di = 0; di < 8; ++di) {
            float x = oacc[di][r];
            u16 hb = rne_bf16(x);
            Ohi[base + di*16] = hb;
            Olo[base + di*16] = rne_bf16(x - bf16_to_f(hb));
        }
    }
}

// ---------------------------------------------------------------------------
extern "C" void kernel_launch(void* const* d_in, const int* in_sizes, int n_in,
                              void* d_out, int out_size, void* d_ws, size_t ws_size,
                              hipStream_t stream)
{
    const float* X  = (const float*)d_in[0];
    const float* Wp[4] = {(const float*)d_in[1], (const float*)d_in[2],
                          (const float*)d_in[3], (const float*)d_in[4]};   // q,k,v,o
    float* outp = (float*)d_out;

    char* ws = (char*)d_ws;
    u16* Xhi = (u16*)ws;                          //  33.5 MB
    u16* Xlo = (u16*)(ws + 33554432);             //  33.5 MB
    u16* Wsp = (u16*)(ws + 67108864);             //  8 x 8.4 MB (hi/lo per W)
    u16* Qbf = (u16*)(ws + 134217728);            //  33.5 MB [B,NH,S,HD]
    u16* Kbf = (u16*)(ws + 167772160);
    u16* Vbf = (u16*)(ws + 201326592);            //  total 235 MB
    u16* Ahi = Xhi;                               // alias: X-split dead after projections
    u16* Alo = Xlo;

    split_kernel<<<(M_*H_/4)/256, 256, 0, stream>>>(X, Xhi, Xlo, M_*H_/4);
    for (int i = 0; i < 4; ++i)
        split_kernel<<<(H_*H_/4)/256, 256, 0, stream>>>(Wp[i],
            Wsp + (size_t)(2*i)*4194304, Wsp + (size_t)(2*i+1)*4194304, H_*H_/4);

    dim3 gg(16, 64);
    gemm_split<<<gg, 256, 0, stream>>>(Xhi, Xlo, Wsp + 0*4194304, Wsp + 1*4194304, Qbf, 0);
    gemm_split<<<gg, 256, 0, stream>>>(Xhi, Xlo, Wsp + 2*4194304, Wsp + 3*4194304, Kbf, 0);
    gemm_split<<<gg, 256, 0, stream>>>(Xhi, Xlo, Wsp + 4*4194304, Wsp + 5*4194304, Vbf, 0);
    rope_bf<<<dim3(32768, 2), 256, 0, stream>>>(Qbf, Kbf);
    attn_mfma<<<dim3(B_*NH_, 4), 256, 0, stream>>>(Qbf, Kbf, Vbf, Ahi, Alo);
    gemm_split<<<gg, 256, 0, stream>>>(Ahi, Alo, Wsp + 6*4194304, Wsp + 7*4194304, outp, 1);
}